// Round 10
// baseline (583.894 us; speedup 1.0000x reference)
//
#include <hip/hip_runtime.h>
#include <stdint.h>

#define NTOK   4096
#define DMODEL 1024
#define HFF    4096
#define NEXP   8
#define BM     256
#define BK     64
#define MAX_MT 40            // max sum_e ceil(cnt_e/256) = 39
#define KT2    (HFF/BK)      // 64 A-tiles per mt in hImg
#define PART_ELEMS ((size_t)MAX_MT * 256 * DMODEL)   // one split-K partial

typedef unsigned int   u32;
typedef unsigned short u16;
typedef u32   u32x4  __attribute__((ext_vector_type(4)));
typedef short s16x8  __attribute__((ext_vector_type(8)));
typedef float f32x4  __attribute__((ext_vector_type(4)));

__device__ __forceinline__ u16 f2bf(float f) {
  u32 u = __builtin_bit_cast(u32, f);
  return (u16)((u + 0x7FFFu + ((u >> 16) & 1u)) >> 16);   // RNE
}
__device__ __forceinline__ u32 cvt_pk_bf16(float lo, float hi) {
  u32 d;
  asm("v_cvt_pk_bf16_f32 %0, %1, %2" : "=v"(d) : "v"(lo), "v"(hi));
  return d;
}

// async global->LDS, 16B/lane; LDS dest = wave-uniform base + lane*16
__device__ __forceinline__ void gld_lds16(const void* g, void* l) {
  __builtin_amdgcn_global_load_lds((const __attribute__((address_space(1))) void*)g,
                                   (__attribute__((address_space(3))) void*)l, 16, 0, 0);
}

// ---- fragment-image format (per 64k x 256n tile, 2048 u32x4 = 32KB) ----------
// entry g*64+l: g=(k>>5)*16+(n>>4), l=((k>>3)&3)*16+(n&15), elem j=k&7 -> T[k][n]
// Half k32 = entries [k32*1024, +1024).

// ---- A images: gather tokens (fp32 x) -> fragment images (256-row tiles) ------
__global__ __launch_bounds__(256) void k_arrange_a(
    const float* __restrict__ x, const int* __restrict__ tok_of_slot,
    const int* __restrict__ mtile_e, u32x4* __restrict__ Ap) {
  const int bid = blockIdx.x;
  const int mt = bid >> 4, kt = bid & 15;     // 16 K-tiles (DMODEL/64)
  if (mtile_e[mt] < 0) return;
  __shared__ u32x4 img[2048];
  u16* imgu = (u16*)img;
  const int tid = threadIdx.x;
  const int lane16 = tid & 15, rp = tid >> 4;
#pragma unroll
  for (int p = 0; p < 16; ++p) {
    const int row = rp + p * 16;
    const int tok = tok_of_slot[mt * BM + row];
    float4 v = *(const float4*)(x + (size_t)tok * DMODEL + kt * BK + lane16 * 4);
    const int g = (lane16 >> 3) * 16 + (row >> 4);
    const int l = ((lane16 >> 1) & 3) * 16 + (row & 15);
    u32* dst = (u32*)(imgu + (size_t)(g * 64 + l) * 8 + (lane16 & 1) * 4);
    dst[0] = (u32)f2bf(v.x) | ((u32)f2bf(v.y) << 16);
    dst[1] = (u32)f2bf(v.z) | ((u32)f2bf(v.w) << 16);
  }
  __syncthreads();
  u32x4* outp = Ap + (size_t)bid * 2048;
#pragma unroll
  for (int c = 0; c < 8; ++c) outp[c * 256 + tid] = img[c * 256 + tid];
}

// ---------------- gating: logits, top-2, softmax(2), counts ----------------
__global__ void k_gating(const float* __restrict__ x, const float* __restrict__ Wg,
                         const float* __restrict__ bg, int* __restrict__ top_idx,
                         float* __restrict__ top_w, int* __restrict__ counts) {
  int t = blockIdx.x, tid = threadIdx.x;
  float acc[NEXP];
#pragma unroll
  for (int e = 0; e < NEXP; ++e) acc[e] = 0.f;
  const float* xr = x + (size_t)t * DMODEL;
  for (int d = tid; d < DMODEL; d += 256) {
    float xv = xr[d];
    const float4* wg = (const float4*)(Wg + d * NEXP);
    float4 a = wg[0], b = wg[1];
    acc[0] += xv * a.x; acc[1] += xv * a.y; acc[2] += xv * a.z; acc[3] += xv * a.w;
    acc[4] += xv * b.x; acc[5] += xv * b.y; acc[6] += xv * b.z; acc[7] += xv * b.w;
  }
#pragma unroll
  for (int e = 0; e < NEXP; ++e)
#pragma unroll
    for (int off = 32; off; off >>= 1) acc[e] += __shfl_down(acc[e], off);
  __shared__ float red[4][NEXP];
  int w = tid >> 6;
  if ((tid & 63) == 0)
    for (int e = 0; e < NEXP; ++e) red[w][e] = acc[e];
  __syncthreads();
  if (tid == 0) {
    float v0 = -1e30f, v1 = -1e30f; int i0 = 0, i1 = 0;
    for (int e = 0; e < NEXP; ++e) {
      float l = red[0][e] + red[1][e] + red[2][e] + red[3][e] + bg[e];
      if (l > v0)      { v1 = v0; i1 = i0; v0 = l; i0 = e; }
      else if (l > v1) { v1 = l; i1 = e; }
    }
    float e1 = expf(v1 - v0);
    float w0 = 1.f / (1.f + e1);
    top_idx[2 * t] = i0; top_idx[2 * t + 1] = i1;
    top_w[2 * t] = w0;   top_w[2 * t + 1] = e1 * w0;
    atomicAdd(&counts[i0], 1); atomicAdd(&counts[i1], 1);
  }
}

// ------------ padded prefix offsets + compact live m-tile map ------------
__global__ void k_offsets(const int* __restrict__ counts, int* __restrict__ poffset,
                          int* __restrict__ mtile_e) {
  if (threadIdx.x == 0 && blockIdx.x == 0) {
    int off = 0, nm = 0;
    for (int e = 0; e < NEXP; ++e) {
      poffset[e] = off;
      int nt = (counts[e] + BM - 1) / BM;
      for (int lt = 0; lt < nt; ++lt) { mtile_e[nm] = e; ++nm; }
      off += nt * BM;
    }
    for (; nm < MAX_MT; ++nm) mtile_e[nm] = -1;
  }
}

// ---------------- scatter tokens to expert slots ----------------
__global__ void k_scatter(const int* __restrict__ top_idx, const int* __restrict__ poffset,
                          int* __restrict__ cursor, int* __restrict__ tok_of_slot,
                          int* __restrict__ token_slot) {
  int t = blockIdx.x * 256 + threadIdx.x;
  if (t >= NTOK) return;
  for (int k = 0; k < 2; ++k) {
    int e = top_idx[2 * t + k];
    int p = atomicAdd(&cursor[e], 1);
    int slot = poffset[e] + p;
    tok_of_slot[slot] = t;
    token_slot[2 * t + k] = slot;
  }
}

// ---------------- grouped GEMM with fused W conversion ----------------
// 256x256xBK64, 512 thr / 8 waves (2M x 4N), acc[8][4]. A: fragment images via
// gld_lds, 4-slab ring (64KB). B: W fp32 read direct (8 x dwordx2/thread/half),
// v_cvt_pk_bf16_f32, ds_write_b128 into 2-slab image ring (32KB). T14 split:
// B loads issued at half start, written after MFMA; lgkmcnt(0)+barrier publish.
// MODE 1: GELU + write h as GEMM2 A-images (2-pass 64KB LDS staging).
// MODE 0: split-K partial, fp32 direct stores, no bias.
template <int MODE>
__global__ __launch_bounds__(512, 1) void k_gemm(
    const u32x4* __restrict__ Ap, int aHalfTot,
    const float* __restrict__ Wsrc, int WN,
    const float* __restrict__ bias, int Nfull, int NT,
    const int* __restrict__ mtile_e, void* __restrict__ outv) {
  const u32 nwg  = gridDim.x;
  const u32 orig = blockIdx.x;
  const u32 gsw  = (orig & 7u) * (nwg >> 3) + (orig >> 3);  // XCD chunks, mt-fastest
  const int mt = (int)(gsw % MAX_MT);
  const u32 q  = gsw / MAX_MT;
  int nt, Hbase, NHk;
  if (MODE) { nt = (int)q; Hbase = 0; NHk = aHalfTot; }
  else      { nt = (int)(q & 3); int kh = (int)(q >> 2);
              Hbase = kh * 43; NHk = (kh == 2) ? 42 : 43; }
  const int e = mtile_e[mt];
  if (e < 0) return;

  __shared__ u32x4 LB[6144];          // 96KB: A ring [0,4096), B ring [4096,6144)
  u32x4* AsR = LB;
  u32x4* BsR = LB + 4096;

  const int tid  = threadIdx.x;
  const int lane = tid & 63;
  const int wv   = tid >> 6;          // 0..7
  const int wm   = wv >> 2;           // 0..1
  const int wn   = wv & 3;            // 0..3

  const u32x4* abase = Ap + ((size_t)mt * aHalfTot + Hbase) * 1024;

  // B staging thread map: entries (bg, bl0), (bg, bl0+1)
  const int bg    = tid >> 5;         // 0..15
  const int bkgrp = (tid >> 3) & 3;   // 0..3
  const int bnp   = tid & 7;          // 0..7
  const int bl0   = bkgrp * 16 + 2 * bnp;
  const float* bcol = Wsrc + (size_t)e * aHalfTot * 32 * WN   // expert base (K = halves*32)
                    + nt * 256 + bg * 16 + 2 * bnp;

  auto stageA = [&](int Hs) {
    const u32x4* sa = abase + (size_t)Hs * 1024;
    gld_lds16(sa + (wv * 2 + 0) * 64 + lane, &AsR[(Hs & 3) * 1024 + (wv * 2 + 0) * 64]);
    gld_lds16(sa + (wv * 2 + 1) * 64 + lane, &AsR[(Hs & 3) * 1024 + (wv * 2 + 1) * 64]);
  };

  f32x4 acc[8][4] = {};

  // ---- prologue: A slabs 0-2 in flight; B(0) loaded+converted+written
  stageA(0); stageA(1); stageA(2);
  {
    const float* rp = bcol + (size_t)(Hbase * 32 + bkgrp * 8) * WN;
    float2 br[8];
#pragma unroll
    for (int j = 0; j < 8; ++j) br[j] = *(const float2*)(rp + (size_t)j * WN);
    u32x4 w0, w1;
#pragma unroll
    for (int qq = 0; qq < 4; ++qq) {
      w0[qq] = cvt_pk_bf16(br[2 * qq].x, br[2 * qq + 1].x);
      w1[qq] = cvt_pk_bf16(br[2 * qq].y, br[2 * qq + 1].y);
    }
    u32x4* d = BsR + bg * 64 + bl0;
    d[0] = w0; d[1] = w1;
  }
  asm volatile("s_waitcnt lgkmcnt(0)" ::: "memory");
  __builtin_amdgcn_sched_barrier(0);

  for (int H = 0; H < NHk; ++H) {
    asm volatile("s_waitcnt vmcnt(4)" ::: "memory");   // A(H) landed; H+1,H+2 fly
    __builtin_amdgcn_sched_barrier(0);
    __builtin_amdgcn_s_barrier();     // A slab H + B slab H published everywhere
    __builtin_amdgcn_sched_barrier(0);
    const u32x4* Ah = AsR + (H & 3) * 1024;
    const u32x4* Bh = BsR + (H & 1) * 1024;
    const bool doB = (H + 1 < NHk);
    float2 br[8];
    if (doB) {                        // issue B(H+1) loads early (T14)
      const float* rp = bcol + (size_t)((Hbase + H + 1) * 32 + bkgrp * 8) * WN;
#pragma unroll
      for (int j = 0; j < 8; ++j) br[j] = *(const float2*)(rp + (size_t)j * WN);
    }
    if (H + 3 < NHk) stageA(H + 3);
    __builtin_amdgcn_sched_barrier(0); // pin load-issue cluster before compute
    s16x8 af[8], bf_[4];
#pragma unroll
    for (int ni = 0; ni < 4; ++ni)
      bf_[ni] = __builtin_bit_cast(s16x8, Bh[(wn * 4 + ni) * 64 + lane]);
#pragma unroll
    for (int mi = 0; mi < 8; ++mi)
      af[mi] = __builtin_bit_cast(s16x8, Ah[(wm * 8 + mi) * 64 + lane]);
    __builtin_amdgcn_s_setprio(1);
#pragma unroll
    for (int mi = 0; mi < 8; ++mi)
#pragma unroll
      for (int ni = 0; ni < 4; ++ni)
        acc[mi][ni] = __builtin_amdgcn_mfma_f32_16x16x32_bf16(af[mi], bf_[ni], acc[mi][ni], 0, 0, 0);
    __builtin_amdgcn_s_setprio(0);
    __builtin_amdgcn_sched_barrier(0);
    if (doB) {                        // convert + write B(H+1) late
      u32x4 w0, w1;
#pragma unroll
      for (int qq = 0; qq < 4; ++qq) {
        w0[qq] = cvt_pk_bf16(br[2 * qq].x, br[2 * qq + 1].x);
        w1[qq] = cvt_pk_bf16(br[2 * qq].y, br[2 * qq + 1].y);
      }
      u32x4* d = BsR + ((H + 1) & 1) * 1024 + bg * 64 + bl0;
      d[0] = w0; d[1] = w1;
    }
    asm volatile("s_waitcnt lgkmcnt(0)" ::: "memory");  // publish B writes
    __builtin_amdgcn_sched_barrier(0);
  }

  __syncthreads();                    // LDS free for epilogue

  const int rbase = ((lane >> 4) << 2);
  const int c16 = lane & 15;
  if (MODE) {
    // GELU + bias; 2-pass image staging (2 x 32KB tiles per pass)
    u16* cimg = (u16*)LB;
    float bv[4];
#pragma unroll
    for (int ni = 0; ni < 4; ++ni)
      bv[ni] = bias[(size_t)e * Nfull + nt * 256 + wn * 64 + ni * 16 + c16];
    u16* hImg = (u16*)outv;
#pragma unroll
    for (int p = 0; p < 2; ++p) {
      if ((wn >> 1) == p) {
#pragma unroll
        for (int mi = 0; mi < 8; ++mi)
#pragma unroll
          for (int ni = 0; ni < 4; ++ni)
#pragma unroll
            for (int r = 0; r < 4; ++r) {
              const int row = wm * 128 + mi * 16 + rbase + r;
              const int colp = (wn & 1) * 64 + ni * 16 + c16;  // 0..127
              float v = acc[mi][ni][r] + bv[ni];
              v = 0.5f * v * (1.0f + erff(v * 0.70710678118654752f));
              const int k = colp & 63;
              const int ent = (colp >> 6) * 2048
                            + ((k >> 5) * 16 + (row >> 4)) * 64
                            + ((k >> 3) & 3) * 16 + (row & 15);
              cimg[ent * 8 + (k & 7)] = f2bf(v);
            }
      }
      __syncthreads();
      u32x4* o = (u32x4*)hImg + ((size_t)mt * KT2 + nt * 4 + p * 2) * 2048;
#pragma unroll
      for (int c = 0; c < 8; ++c) o[c * 512 + tid] = LB[c * 512 + tid];
      __syncthreads();
    }
  } else {
    // fp32 partial, no bias
    const int kh = Hbase / 43;
    float* o = (float*)outv + (size_t)kh * PART_ELEMS
             + (size_t)mt * 256 * DMODEL + nt * 256;
#pragma unroll
    for (int mi = 0; mi < 8; ++mi)
#pragma unroll
      for (int ni = 0; ni < 4; ++ni)
#pragma unroll
        for (int r = 0; r < 4; ++r) {
          const int row = wm * 128 + mi * 16 + rbase + r;
          o[(size_t)row * DMODEL + wn * 64 + ni * 16 + c16] = acc[mi][ni][r];
        }
  }
}

// -------- combine: sum 3 partials + bias, top-2 weight, residual, LayerNorm ----
__global__ void k_combine_ln(const float* __restrict__ x, const float* __restrict__ part,
                             const int* __restrict__ token_slot, const int* __restrict__ top_idx,
                             const float* __restrict__ top_w, const float* __restrict__ b2,
                             const float* __restrict__ gamma, const float* __restrict__ beta,
                             float* __restrict__ out) {
  int t = blockIdx.x, tid = threadIdx.x;
  int s0 = token_slot[2 * t], s1 = token_slot[2 * t + 1];
  int e0 = top_idx[2 * t],   e1 = top_idx[2 * t + 1];
  float w0 = top_w[2 * t], w1 = top_w[2 * t + 1];
  const float4* P = (const float4*)part;
  const size_t P4 = PART_ELEMS / 4;
  float4 xv = ((const float4*)(x + (size_t)t * DMODEL))[tid];
  size_t i0 = (size_t)s0 * 256 + tid, i1 = (size_t)s1 * 256 + tid;
  float4 a0 = P[i0], a1 = P[i0 + P4], a2 = P[i0 + 2 * P4];
  float4 c0 = P[i1], c1 = P[i1 + P4], c2 = P[i1 + 2 * P4];
  float4 bb0 = ((const float4*)(b2 + (size_t)e0 * DMODEL))[tid];
  float4 bb1 = ((const float4*)(b2 + (size_t)e1 * DMODEL))[tid];
  float r0 = xv.x + w0 * (a0.x + a1.x + a2.x + bb0.x) + w1 * (c0.x + c1.x + c2.x + bb1.x);
  float r1 = xv.y + w0 * (a0.y + a1.y + a2.y + bb0.y) + w1 * (c0.y + c1.y + c2.y + bb1.y);
  float r2 = xv.z + w0 * (a0.z + a1.z + a2.z + bb0.z) + w1 * (c0.z + c1.z + c2.z + bb1.z);
  float r3 = xv.w + w0 * (a0.w + a1.w + a2.w + bb0.w) + w1 * (c0.w + c1.w + c2.w + bb1.w);
  float s  = r0 + r1 + r2 + r3;
  float sq = r0 * r0 + r1 * r1 + r2 * r2 + r3 * r3;
#pragma unroll
  for (int off = 32; off; off >>= 1) { s += __shfl_down(s, off); sq += __shfl_down(sq, off); }
  __shared__ float rs[4], rq[4];
  __shared__ float mu_s, rsig_s;
  int w = tid >> 6;
  if ((tid & 63) == 0) { rs[w] = s; rq[w] = sq; }
  __syncthreads();
  if (tid == 0) {
    float S = rs[0] + rs[1] + rs[2] + rs[3];
    float Q = rq[0] + rq[1] + rq[2] + rq[3];
    float mu  = S * (1.0f / DMODEL);
    float var = Q * (1.0f / DMODEL) - mu * mu;
    mu_s = mu; rsig_s = rsqrtf(var + 1e-5f);
  }
  __syncthreads();
  float mu = mu_s, rsig = rsig_s;
  float4 gv = ((const float4*)gamma)[tid];
  float4 bv = ((const float4*)beta)[tid];
  float4 o;
  o.x = (r0 - mu) * rsig * gv.x + bv.x;
  o.y = (r1 - mu) * rsig * gv.y + bv.y;
  o.z = (r2 - mu) * rsig * gv.z + bv.z;
  o.w = (r3 - mu) * rsig * gv.w + bv.w;
  ((float4*)(out + (size_t)t * DMODEL))[tid] = o;
}

// ---------------- launch ----------------
extern "C" void kernel_launch(void* const* d_in, const int* in_sizes, int n_in,
                              void* d_out, int out_size, void* d_ws, size_t ws_size,
                              hipStream_t stream) {
  const float* x     = (const float*)d_in[0];
  const float* Wg    = (const float*)d_in[1];
  const float* bg    = (const float*)d_in[2];
  const float* W1    = (const float*)d_in[3];
  const float* b1    = (const float*)d_in[4];
  const float* W2    = (const float*)d_in[5];
  const float* b2    = (const float*)d_in[6];
  const float* gamma = (const float*)d_in[7];
  const float* beta  = (const float*)d_in[8];
  float* out = (float*)d_out;

  // workspace ~231MB: Ap1 21 + hImg 84 + partials 126 + meta
  char* ws = (char*)d_ws;
  u32x4* Ap1  = (u32x4*)ws;                                  // 40*16*2048*16 = 21.0MB
  char* p = ws + (size_t)MAX_MT * 16 * 2048 * 16;
  u16*   hImg = (u16*)p;  p += (size_t)MAX_MT * KT2 * 2048 * 16;   // 83.9MB
  float* part = (float*)p; p += 3 * PART_ELEMS * 4;                 // 125.8MB
  int*   meta = (int*)p;
  int*   counts      = meta;
  int*   cursor      = counts + 8;
  int*   poffset     = cursor + 8;
  int*   tok_of_slot = poffset + 8;
  int*   mtile_e     = tok_of_slot + MAX_MT * BM;
  int*   token_slot  = mtile_e + MAX_MT;
  int*   top_idx     = token_slot + 2 * NTOK;
  float* top_w       = (float*)(top_idx + 2 * NTOK);
  (void)ws_size; (void)in_sizes; (void)n_in; (void)out_size;

  hipMemsetAsync(meta, 0, (size_t)(24 + MAX_MT * BM) * 4, stream);

  k_gating<<<NTOK, 256, 0, stream>>>(x, Wg, bg, top_idx, top_w, counts);
  k_offsets<<<1, 1, 0, stream>>>(counts, poffset, mtile_e);
  k_scatter<<<NTOK / 256, 256, 0, stream>>>(top_idx, poffset, cursor, tok_of_slot, token_slot);
  k_arrange_a<<<MAX_MT * 16, 256, 0, stream>>>(x, tok_of_slot, mtile_e, Ap1);

  // GEMM1: 16 nt x 40 mt = 640 blocks; B = W1 fp32 direct; GELU; h -> images
  k_gemm<1><<<(HFF / 256) * MAX_MT, 512, 0, stream>>>(
      Ap1, 32, W1, HFF, b1, HFF, HFF / 256, mtile_e, (void*)hImg);

  // GEMM2: 4 nt x 40 mt x 3 kh = 480 blocks; B = W2 fp32 direct; fp32 partials
  k_gemm<0><<<(DMODEL / 256) * MAX_MT * 3, 512, 0, stream>>>(
      (const u32x4*)hImg, 128, W2, DMODEL, nullptr, DMODEL, DMODEL / 256,
      mtile_e, (void*)part);

  k_combine_ln<<<NTOK, 256, 0, stream>>>(x, part, token_slot, top_idx, top_w,
                                         b2, gamma, beta, out);
}

// Round 11
// 507.033 us; speedup vs baseline: 1.1516x; 1.1516x over previous
//
#include <hip/hip_runtime.h>
#include <stdint.h>

#define NTOK   4096
#define DMODEL 1024
#define HFF    4096
#define NEXP   8
#define BM     256
#define BK     64
#define MAX_MT 39            // true bound: 8192/256 + 7 = 39
#define KT1    (DMODEL/BK)   // 16
#define KT2    (HFF/BK)      // 64
#define PART_ELEMS ((size_t)MAX_MT * 256 * DMODEL)   // one split-K partial

typedef unsigned int   u32;
typedef unsigned short u16;
typedef u32   u32x4  __attribute__((ext_vector_type(4)));
typedef short s16x8  __attribute__((ext_vector_type(8)));
typedef float f32x4  __attribute__((ext_vector_type(4)));

__device__ __forceinline__ u16 f2bf(float f) {
  u32 u = __builtin_bit_cast(u32, f);
  return (u16)((u + 0x7FFFu + ((u >> 16) & 1u)) >> 16);   // RNE, finite inputs
}
__device__ __forceinline__ float bf2f(u32 lo16) {
  return __builtin_bit_cast(float, lo16 << 16);
}

// async global->LDS, 16B/lane; LDS dest = wave-uniform base + lane*16
__device__ __forceinline__ void gld_lds16(const void* g, void* l) {
  __builtin_amdgcn_global_load_lds((const __attribute__((address_space(1))) void*)g,
                                   (__attribute__((address_space(3))) void*)l, 16, 0, 0);
}

// ---- fragment-image format (per 64k x 256n tile, 2048 u32x4 = 32KB) ----------
// entry g*64+l: g=(k>>5)*16+(n>>4), l=((k>>3)&3)*16+(n&15), elem j=k&7 -> T[k][n]
// Half k32 of tile t lives at image offset (2*t + k32)*1024 -- linear in halves.

// ------- W [K][N] fp32 -> fragment images, 256-col tiles -----------------------
__global__ __launch_bounds__(256) void k_prearrange(
    const float* __restrict__ W, u32x4* __restrict__ Bp, int K, int N, int NT, int KT) {
  int tile = blockIdx.x;             // (e*NT + nt)*KT + kt
  int kt  = tile % KT; int rem = tile / KT;
  int nt  = rem % NT;  int e   = rem / NT;
  __shared__ u32x4 img4[2048];       // 32KB
  u32* img = (u32*)img4;
  const int tid = threadIdx.x;
  const float* src = W + ((size_t)e * K + (size_t)kt * BK) * N + (size_t)nt * 256;
  const int c4 = (tid & 63) * 4;     // n: 0,4,...,252
  const int k0 = (tid >> 6) * 2;     // 0,2,4,6
#pragma unroll
  for (int p = 0; p < 8; ++p) {
    const int k = k0 + p * 8;        // even
    float4 v0 = *(const float4*)(src + (size_t)k * N + c4);
    float4 v1 = *(const float4*)(src + (size_t)(k + 1) * N + c4);
    u32 w[4] = { (u32)f2bf(v0.x) | ((u32)f2bf(v1.x) << 16),
                 (u32)f2bf(v0.y) | ((u32)f2bf(v1.y) << 16),
                 (u32)f2bf(v0.z) | ((u32)f2bf(v1.z) << 16),
                 (u32)f2bf(v0.w) | ((u32)f2bf(v1.w) << 16) };
#pragma unroll
    for (int q = 0; q < 4; ++q) {
      const int n = c4 + q;
      const int ent = ((k >> 5) * 16 + (n >> 4)) * 64 + ((k >> 3) & 3) * 16 + (n & 15);
      img[ent * 4 + ((k & 7) >> 1)] = w[q];
    }
  }
  __syncthreads();
  u32x4* outp = Bp + (size_t)tile * 2048;
#pragma unroll
  for (int c = 0; c < 8; ++c) outp[c * 256 + tid] = img4[c * 256 + tid];
}

// ---- A images: gather tokens (fp32 x) -> fragment images (256-row tiles) ------
__global__ __launch_bounds__(256) void k_arrange_a(
    const float* __restrict__ x, const int* __restrict__ tok_of_slot,
    const int* __restrict__ mtile_e, u32x4* __restrict__ Ap) {
  const int bid = blockIdx.x;
  const int mt = bid >> 4, kt = bid & 15;     // 16 K-tiles
  if (mtile_e[mt] < 0) return;
  __shared__ u32x4 img[2048];
  u16* imgu = (u16*)img;
  const int tid = threadIdx.x;
  const int lane16 = tid & 15, rp = tid >> 4;
#pragma unroll
  for (int p = 0; p < 16; ++p) {
    const int row = rp + p * 16;
    const int tok = tok_of_slot[mt * BM + row];
    float4 v = *(const float4*)(x + (size_t)tok * DMODEL + kt * BK + lane16 * 4);
    const int g = (lane16 >> 3) * 16 + (row >> 4);
    const int l = ((lane16 >> 1) & 3) * 16 + (row & 15);
    u32* dst = (u32*)(imgu + (size_t)(g * 64 + l) * 8 + (lane16 & 1) * 4);
    dst[0] = (u32)f2bf(v.x) | ((u32)f2bf(v.y) << 16);
    dst[1] = (u32)f2bf(v.z) | ((u32)f2bf(v.w) << 16);
  }
  __syncthreads();
  u32x4* outp = Ap + (size_t)bid * 2048;
#pragma unroll
  for (int c = 0; c < 8; ++c) outp[c * 256 + tid] = img[c * 256 + tid];
}

// ---------------- gating: logits, top-2, softmax(2), counts ----------------
__global__ void k_gating(const float* __restrict__ x, const float* __restrict__ Wg,
                         const float* __restrict__ bg, int* __restrict__ top_idx,
                         float* __restrict__ top_w, int* __restrict__ counts) {
  int t = blockIdx.x, tid = threadIdx.x;
  float acc[NEXP];
#pragma unroll
  for (int e = 0; e < NEXP; ++e) acc[e] = 0.f;
  const float* xr = x + (size_t)t * DMODEL;
  for (int d = tid; d < DMODEL; d += 256) {
    float xv = xr[d];
    const float4* wg = (const float4*)(Wg + d * NEXP);
    float4 a = wg[0], b = wg[1];
    acc[0] += xv * a.x; acc[1] += xv * a.y; acc[2] += xv * a.z; acc[3] += xv * a.w;
    acc[4] += xv * b.x; acc[5] += xv * b.y; acc[6] += xv * b.z; acc[7] += xv * b.w;
  }
#pragma unroll
  for (int e = 0; e < NEXP; ++e)
#pragma unroll
    for (int off = 32; off; off >>= 1) acc[e] += __shfl_down(acc[e], off);
  __shared__ float red[4][NEXP];
  int w = tid >> 6;
  if ((tid & 63) == 0)
    for (int e = 0; e < NEXP; ++e) red[w][e] = acc[e];
  __syncthreads();
  if (tid == 0) {
    float v0 = -1e30f, v1 = -1e30f; int i0 = 0, i1 = 0;
    for (int e = 0; e < NEXP; ++e) {
      float l = red[0][e] + red[1][e] + red[2][e] + red[3][e] + bg[e];
      if (l > v0)      { v1 = v0; i1 = i0; v0 = l; i0 = e; }
      else if (l > v1) { v1 = l; i1 = e; }
    }
    float e1 = expf(v1 - v0);
    float w0 = 1.f / (1.f + e1);
    top_idx[2 * t] = i0; top_idx[2 * t + 1] = i1;
    top_w[2 * t] = w0;   top_w[2 * t + 1] = e1 * w0;
    atomicAdd(&counts[i0], 1); atomicAdd(&counts[i1], 1);
  }
}

// ------------ padded prefix offsets + compact live m-tile map ------------
__global__ void k_offsets(const int* __restrict__ counts, int* __restrict__ poffset,
                          int* __restrict__ mtile_e) {
  if (threadIdx.x == 0 && blockIdx.x == 0) {
    int off = 0, nm = 0;
    for (int e = 0; e < NEXP; ++e) {
      poffset[e] = off;
      int nt = (counts[e] + BM - 1) / BM;
      for (int lt = 0; lt < nt; ++lt) { mtile_e[nm] = e; ++nm; }
      off += nt * BM;
    }
    for (; nm < MAX_MT; ++nm) mtile_e[nm] = -1;
  }
}

// ---------------- scatter tokens to expert slots ----------------
__global__ void k_scatter(const int* __restrict__ top_idx, const int* __restrict__ poffset,
                          int* __restrict__ cursor, int* __restrict__ tok_of_slot,
                          int* __restrict__ token_slot) {
  int t = blockIdx.x * 256 + threadIdx.x;
  if (t >= NTOK) return;
  for (int k = 0; k < 2; ++k) {
    int e = top_idx[2 * t + k];
    int p = atomicAdd(&cursor[e], 1);
    int slot = poffset[e] + p;
    tok_of_slot[slot] = t;
    token_slot[2 * t + k] = slot;
  }
}

// ---------------- grouped GEMM, R8 ring schedule (best measured) ----------------
// 256x256xBK64 tile, 512 threads / 8 waves (2M x 4N), acc[8][4] per wave.
// 4-deep half-K-slab ring per operand (128KB LDS). Per half H: counted vmcnt
// (8/4/0 tail) -> raw s_barrier -> {stageA(H+3) | ds_read | 16 MFMA @prio1}
// -> {stageB(H+3) | ds_read | 16 MFMA @prio1}.  halvesK = total K halves of
// the operand images. MODE 1: full K, GELU+bias, writes h as GEMM2 A-images.
// MODE 0: split-K=2 (kh from grid), fp32 partial store, bias deferred.
template <int MODE>
__global__ __launch_bounds__(512, 2) void k_gemm(
    const u32x4* __restrict__ Ap, int halvesK,
    const u32x4* __restrict__ Bp,
    const float* __restrict__ bias, int Nfull, int NT,
    const int* __restrict__ mtile_e, void* __restrict__ outv) {
  const u32 nwg  = gridDim.x;
  const u32 orig = blockIdx.x;
  const u32 gsw  = (orig & 7u) * (nwg >> 3) + (orig >> 3);  // XCD chunks, mt-fastest
  const int mt = (int)(gsw % MAX_MT);
  const u32 q  = gsw / MAX_MT;
  int nt, kh, Hbase, NH;
  if (MODE) { nt = (int)q; kh = 0; Hbase = 0; NH = halvesK; }
  else      { nt = (int)(q & 3); kh = (int)(q >> 2);
              NH = halvesK / 2; Hbase = kh * NH; }
  const int e = mtile_e[mt];
  if (e < 0) return;

  __shared__ u32x4 LB[8192];          // 128KB; A ring [0,4096), B ring [4096,8192)
  u32x4* AsR = LB;
  u32x4* BsR = LB + 4096;

  const int tid  = threadIdx.x;
  const int lane = tid & 63;
  const int wv   = tid >> 6;          // 0..7
  const int wm   = wv >> 2;           // 0..1
  const int wn   = wv & 3;            // 0..3

  const u32x4* abase = Ap + ((size_t)mt * halvesK + Hbase) * 1024;
  const u32x4* bbase = Bp + ((size_t)(e * NT + nt) * halvesK + Hbase) * 1024;

  auto stageA = [&](int Hs) {
    const u32x4* sa = abase + (size_t)Hs * 1024;
    const int s = Hs & 3;
    gld_lds16(sa + (wv * 2 + 0) * 64 + lane, &AsR[s * 1024 + (wv * 2 + 0) * 64]);
    gld_lds16(sa + (wv * 2 + 1) * 64 + lane, &AsR[s * 1024 + (wv * 2 + 1) * 64]);
  };
  auto stageB = [&](int Hs) {
    const u32x4* sb = bbase + (size_t)Hs * 1024;
    const int s = Hs & 3;
    gld_lds16(sb + (wv * 2 + 0) * 64 + lane, &BsR[s * 1024 + (wv * 2 + 0) * 64]);
    gld_lds16(sb + (wv * 2 + 1) * 64 + lane, &BsR[s * 1024 + (wv * 2 + 1) * 64]);
  };

  f32x4 acc[8][4] = {};

  stageA(0); stageB(0); stageA(1); stageB(1); stageA(2); stageB(2);  // 12 in flight

  for (int H = 0; H < NH; ++H) {
    const int rem = NH - 1 - H;
    if (rem >= 2)      asm volatile("s_waitcnt vmcnt(8)" ::: "memory");
    else if (rem == 1) asm volatile("s_waitcnt vmcnt(4)" ::: "memory");
    else               asm volatile("s_waitcnt vmcnt(0)" ::: "memory");
    __builtin_amdgcn_sched_barrier(0);
    __builtin_amdgcn_s_barrier();     // slab H complete in all waves; H-1 readers done
    __builtin_amdgcn_sched_barrier(0);
    const u32x4* Ah = AsR + (H & 3) * 1024;
    const u32x4* Bh = BsR + (H & 3) * 1024;
    const bool st = (H + 3 < NH);
    // ---- phase 0: stage A of H+3, read b[0..3]+a[0..3], 16 MFMA
    if (st) stageA(H + 3);
    __builtin_amdgcn_sched_barrier(0);
    s16x8 a[4], b[4];
#pragma unroll
    for (int ni = 0; ni < 4; ++ni)
      b[ni] = __builtin_bit_cast(s16x8, Bh[(wn * 4 + ni) * 64 + lane]);
#pragma unroll
    for (int mi = 0; mi < 4; ++mi)
      a[mi] = __builtin_bit_cast(s16x8, Ah[(wm * 8 + mi) * 64 + lane]);
    __builtin_amdgcn_s_setprio(1);
#pragma unroll
    for (int mi = 0; mi < 4; ++mi)
#pragma unroll
      for (int ni = 0; ni < 4; ++ni)
        acc[mi][ni] = __builtin_amdgcn_mfma_f32_16x16x32_bf16(a[mi], b[ni], acc[mi][ni], 0, 0, 0);
    __builtin_amdgcn_s_setprio(0);
    __builtin_amdgcn_sched_barrier(0);
    // ---- phase 1: stage B of H+3, read a[4..7], 16 MFMA
    if (st) stageB(H + 3);
    __builtin_amdgcn_sched_barrier(0);
#pragma unroll
    for (int mi = 0; mi < 4; ++mi)
      a[mi] = __builtin_bit_cast(s16x8, Ah[(wm * 8 + 4 + mi) * 64 + lane]);
    __builtin_amdgcn_s_setprio(1);
#pragma unroll
    for (int mi = 0; mi < 4; ++mi)
#pragma unroll
      for (int ni = 0; ni < 4; ++ni)
        acc[4 + mi][ni] = __builtin_amdgcn_mfma_f32_16x16x32_bf16(a[mi], b[ni], acc[4 + mi][ni], 0, 0, 0);
    __builtin_amdgcn_s_setprio(0);
  }

  __syncthreads();                    // all reads done; LDS free for epilogue

  const int rbase = ((lane >> 4) << 2);
  const int c16 = lane & 15;
  if (MODE) {
    // ---- GELU+bias; scatter to image layout in LDS; write 4 GEMM2 A-tiles
    u16* cimg = (u16*)LB;
    float bv[4];
#pragma unroll
    for (int ni = 0; ni < 4; ++ni)
      bv[ni] = bias[(size_t)e * Nfull + nt * 256 + wn * 64 + ni * 16 + c16];
#pragma unroll
    for (int mi = 0; mi < 8; ++mi)
#pragma unroll
      for (int ni = 0; ni < 4; ++ni)
#pragma unroll
        for (int r = 0; r < 4; ++r) {
          const int row = wm * 128 + mi * 16 + rbase + r;
          const int col = wn * 64 + ni * 16 + c16;
          float v = acc[mi][ni][r] + bv[ni];
          v = 0.5f * v * (1.0f + erff(v * 0.70710678118654752f));
          const int k = col & 63;
          const int ent = (col >> 6) * 2048
                        + ((k >> 5) * 16 + (row >> 4)) * 64
                        + ((k >> 3) & 3) * 16 + (row & 15);
          cimg[ent * 8 + (k & 7)] = f2bf(v);
        }
    __syncthreads();
    u32x4* outp = (u32x4*)outv + ((size_t)mt * KT2 + nt * 4) * 2048;
#pragma unroll
    for (int c = 0; c < 16; ++c) {
      const int idx = c * 512 + tid;
      outp[idx] = LB[idx];
    }
  } else {
    // ---- fp32 split-K partial, no bias
    float* o = (float*)outv + (size_t)kh * PART_ELEMS
             + (size_t)mt * 256 * DMODEL + nt * 256;
#pragma unroll
    for (int mi = 0; mi < 8; ++mi)
#pragma unroll
      for (int ni = 0; ni < 4; ++ni)
#pragma unroll
        for (int r = 0; r < 4; ++r) {
          const int row = wm * 128 + mi * 16 + rbase + r;
          o[(size_t)row * DMODEL + wn * 64 + ni * 16 + c16] = acc[mi][ni][r];
        }
  }
}

// -------- combine: sum 2 partials + bias, top-2 weight, residual, LayerNorm ----
__global__ void k_combine_ln(const float* __restrict__ x, const float* __restrict__ part,
                             const int* __restrict__ token_slot, const int* __restrict__ top_idx,
                             const float* __restrict__ top_w, const float* __restrict__ b2,
                             const float* __restrict__ gamma, const float* __restrict__ beta,
                             float* __restrict__ out) {
  int t = blockIdx.x, tid = threadIdx.x;
  int s0 = token_slot[2 * t], s1 = token_slot[2 * t + 1];
  int e0 = top_idx[2 * t],   e1 = top_idx[2 * t + 1];
  float w0 = top_w[2 * t], w1 = top_w[2 * t + 1];
  const float4* P = (const float4*)part;
  const size_t P4 = PART_ELEMS / 4;
  float4 xv = ((const float4*)(x + (size_t)t * DMODEL))[tid];
  size_t i0 = (size_t)s0 * 256 + tid, i1 = (size_t)s1 * 256 + tid;
  float4 a0 = P[i0], a1 = P[i0 + P4];
  float4 c0 = P[i1], c1 = P[i1 + P4];
  float4 bb0 = ((const float4*)(b2 + (size_t)e0 * DMODEL))[tid];
  float4 bb1 = ((const float4*)(b2 + (size_t)e1 * DMODEL))[tid];
  float r0 = xv.x + w0 * (a0.x + a1.x + bb0.x) + w1 * (c0.x + c1.x + bb1.x);
  float r1 = xv.y + w0 * (a0.y + a1.y + bb0.y) + w1 * (c0.y + c1.y + bb1.y);
  float r2 = xv.z + w0 * (a0.z + a1.z + bb0.z) + w1 * (c0.z + c1.z + bb1.z);
  float r3 = xv.w + w0 * (a0.w + a1.w + bb0.w) + w1 * (c0.w + c1.w + bb1.w);
  float s  = r0 + r1 + r2 + r3;
  float sq = r0 * r0 + r1 * r1 + r2 * r2 + r3 * r3;
#pragma unroll
  for (int off = 32; off; off >>= 1) { s += __shfl_down(s, off); sq += __shfl_down(sq, off); }
  __shared__ float rs[4], rq[4];
  __shared__ float mu_s, rsig_s;
  int w = tid >> 6;
  if ((tid & 63) == 0) { rs[w] = s; rq[w] = sq; }
  __syncthreads();
  if (tid == 0) {
    float S = rs[0] + rs[1] + rs[2] + rs[3];
    float Q = rq[0] + rq[1] + rq[2] + rq[3];
    float mu  = S * (1.0f / DMODEL);
    float var = Q * (1.0f / DMODEL) - mu * mu;
    mu_s = mu; rsig_s = rsqrtf(var + 1e-5f);
  }
  __syncthreads();
  float mu = mu_s, rsig = rsig_s;
  float4 gv = ((const float4*)gamma)[tid];
  float4 bv = ((const float4*)beta)[tid];
  float4 o;
  o.x = (r0 - mu) * rsig * gv.x + bv.x;
  o.y = (r1 - mu) * rsig * gv.y + bv.y;
  o.z = (r2 - mu) * rsig * gv.z + bv.z;
  o.w = (r3 - mu) * rsig * gv.w + bv.w;
  ((float4*)(out + (size_t)t * DMODEL))[tid] = o;
}

// ---------------- launch ----------------
extern "C" void kernel_launch(void* const* d_in, const int* in_sizes, int n_in,
                              void* d_out, int out_size, void* d_ws, size_t ws_size,
                              hipStream_t stream) {
  const float* x     = (const float*)d_in[0];
  const float* Wg    = (const float*)d_in[1];
  const float* bg    = (const float*)d_in[2];
  const float* W1    = (const float*)d_in[3];
  const float* b1    = (const float*)d_in[4];
  const float* W2    = (const float*)d_in[5];
  const float* b2    = (const float*)d_in[6];
  const float* gamma = (const float*)d_in[7];
  const float* beta  = (const float*)d_in[8];
  float* out = (float*)d_out;

  // workspace ~236.8MB (<= 237.1MB proven in R1):
  // [Ap1 19.5MiB | Bp1 64MiB][Bp2 64MiB][hImg 78MiB][meta]
  // part (78MiB, 2 x fp32 partials) aliases [Ap1|Bp1] (dead after GEMM1).
  char* ws = (char*)d_ws;
  const size_t szAp1 = (size_t)MAX_MT * KT1 * 2048 * 16;         // 19.5 MiB
  const size_t szBp  = (size_t)NEXP * DMODEL * HFF * 2;          // 64 MiB
  u32x4* Ap1  = (u32x4*)ws;
  u32x4* Bp1  = (u32x4*)(ws + szAp1);
  float* part = (float*)ws;                                      // alias
  u32x4* Bp2  = (u32x4*)(ws + szAp1 + szBp);
  char* p = ws + szAp1 + 2 * szBp;
  u16*   hImg = (u16*)p;  p += (size_t)MAX_MT * KT2 * 2048 * 16; // 78 MiB
  int*   meta = (int*)p;
  int*   counts      = meta;
  int*   cursor      = counts + 8;
  int*   poffset     = cursor + 8;
  int*   tok_of_slot = poffset + 8;
  int*   mtile_e     = tok_of_slot + MAX_MT * BM;
  int*   token_slot  = mtile_e + MAX_MT;
  int*   top_idx     = token_slot + 2 * NTOK;
  float* top_w       = (float*)(top_idx + 2 * NTOK);
  (void)ws_size; (void)in_sizes; (void)n_in; (void)out_size;

  hipMemsetAsync(meta, 0, (size_t)(24 + MAX_MT * BM) * 4, stream);

  k_gating<<<NTOK, 256, 0, stream>>>(x, Wg, bg, top_idx, top_w, counts);
  k_offsets<<<1, 1, 0, stream>>>(counts, poffset, mtile_e);
  k_scatter<<<NTOK / 256, 256, 0, stream>>>(top_idx, poffset, cursor, tok_of_slot, token_slot);

  // W1 [8][1024][4096] -> Bp1 (NT=16, KT=16); W2 [8][4096][1024] -> Bp2 (NT=4, KT=64)
  k_prearrange<<<NEXP * (HFF / 256) * KT1, 256, 0, stream>>>(W1, Bp1, DMODEL, HFF, HFF / 256, KT1);
  k_prearrange<<<NEXP * (DMODEL / 256) * KT2, 256, 0, stream>>>(W2, Bp2, HFF, DMODEL, DMODEL / 256, KT2);
  // gathered token images (39 x 16 = 624 blocks)
  k_arrange_a<<<MAX_MT * KT1, 256, 0, stream>>>(x, tok_of_slot, mtile_e, Ap1);

  // GEMM1: 16 nt x 39 mt = 624 blocks (8*78); GELU; writes h as GEMM2 A-images
  k_gemm<1><<<(HFF / 256) * MAX_MT, 512, 0, stream>>>(
      Ap1, 2 * KT1, Bp1, b1, HFF, HFF / 256, mtile_e, (void*)hImg);

  // GEMM2: 4 nt x 39 mt x 2 kh = 312 blocks (8*39); fp32 partials (aliases Ap1/Bp1)
  k_gemm<0><<<(DMODEL / 256) * MAX_MT * 2, 512, 0, stream>>>(
      (const u32x4*)hImg, 2 * KT2, Bp2, nullptr, DMODEL, DMODEL / 256,
      mtile_e, (void*)part);

  k_combine_ln<<<NTOK, 256, 0, stream>>>(x, part, token_slot, top_idx, top_w,
                                         b2, gamma, beta, out);
}